// Round 4
// baseline (80.324 us; speedup 1.0000x reference)
//
#include <hip/hip_runtime.h>
#include <stdint.h>
#include <stddef.h>

#define NCELLS (512 * 512)   // 262144 grid cells
#define CG 64                // grid embedding channels
#define CPC 64               // point-cloud channels
#define CIN 128              // concat width
#define CH 32                // hidden width
#define COUT 3

// Fused network: out = W_eff @ [emb; pc] + b_eff, W_eff = Z_w@Y_w (3x128).
// GZ4[p] = W_eff[:, :64] @ grid[:, p] + b_eff  (4 MiB table -> L2-resident)
// main:   out[i] = GZ4[idx[i]].xyz + W_eff[:, 64:] @ pc[i]
//
// Streaming data (pc, idx, grid, out) uses nontemporal loads/stores so the
// per-XCD L2 stays dedicated to the GZ gather table.

typedef float f32x4 __attribute__((ext_vector_type(4)));

__device__ inline f32x4 nt_load4(const float* p) {
    return __builtin_nontemporal_load((const f32x4*)p);
}

// ---------------------------------------------------------------------------
// prep: fold the two linear layers; detect idx element width (int64 vs int32:
// aligned u64 reads of an int64 index array are < 2^18 since idx < 262144;
// for int32 they combine two random indices -> >= 2^32 almost surely).
// ---------------------------------------------------------------------------
__global__ void prep_kernel(const float* __restrict__ Yw,   // (32,128)
                            const float* __restrict__ Yb,   // (32,)
                            const float* __restrict__ Zw,   // (3,32)
                            const float* __restrict__ Zb,   // (3,)
                            const unsigned long long* __restrict__ idx_as_u64,
                            float4* __restrict__ Wemb4,     // [64]
                            float4* __restrict__ Wpc4,      // [64]
                            float4* __restrict__ beff,      // [1]
                            int* __restrict__ flag_is64) {
    int c = threadIdx.x;           // 0..127
    if (c < CIN) {
        float w0 = 0.f, w1 = 0.f, w2 = 0.f;
#pragma unroll
        for (int j = 0; j < CH; ++j) {
            float y = Yw[j * CIN + c];
            w0 = fmaf(Zw[0 * CH + j], y, w0);
            w1 = fmaf(Zw[1 * CH + j], y, w1);
            w2 = fmaf(Zw[2 * CH + j], y, w2);
        }
        float4 v = make_float4(w0, w1, w2, 0.f);
        if (c < CG) Wemb4[c] = v;
        else        Wpc4[c - CG] = v;
    }
    if (c == 0) {
        float b0 = Zb[0], b1 = Zb[1], b2 = Zb[2];
#pragma unroll
        for (int j = 0; j < CH; ++j) {
            float y = Yb[j];
            b0 = fmaf(Zw[0 * CH + j], y, b0);
            b1 = fmaf(Zw[1 * CH + j], y, b1);
            b2 = fmaf(Zw[2 * CH + j], y, b2);
        }
        *beff = make_float4(b0, b1, b2, 0.f);

        int is64 = 1;
        for (int i = 0; i < 8; ++i) {
            if (idx_as_u64[i] >= (unsigned long long)NCELLS) { is64 = 0; break; }
        }
        *flag_is64 = is64;
    }
}

// ---------------------------------------------------------------------------
// GZ table. 1 cell/thread, 1024 blocks. grid reads nontemporal (no reuse).
// ---------------------------------------------------------------------------
__global__ void __launch_bounds__(256)
gz_kernel(const float* __restrict__ grid,     // (64, 262144)
          const float4* __restrict__ Wemb4,   // [64] (wave-uniform -> scalar)
          const float4* __restrict__ beff,
          float4* __restrict__ GZ4) {
    int p = blockIdx.x * blockDim.x + threadIdx.x;
    if (p >= NCELLS) return;

    float4 b = *beff;
    float a0 = b.x, a1 = b.y, a2 = b.z;

#pragma unroll 8
    for (int c = 0; c < CG; ++c) {
        float g = __builtin_nontemporal_load(grid + (size_t)c * NCELLS + p);
        float4 w = Wemb4[c];
        a0 = fmaf(w.x, g, a0);
        a1 = fmaf(w.y, g, a1);
        a2 = fmaf(w.z, g, a2);
    }
    GZ4[p] = make_float4(a0, a1, a2, 0.f);
}

// ---------------------------------------------------------------------------
// Main: 8 lanes per point; wave VMEM instr = 8 points x 128B contiguous
// half-rows (8 fully-consumed lines). Leader's idx load + GZ gather issued
// at the TOP of the iteration so their latency hides under the FMA block.
// pc/idx nontemporal; GZ gather cached (we WANT it in L2); out nontemporal.
// ---------------------------------------------------------------------------
__global__ void __launch_bounds__(256)
main_kernel(const float4* __restrict__ GZ4,
            const float* __restrict__ pc,       // (N,64)
            const void* __restrict__ idx_raw,
            const float4* __restrict__ Wpc4,    // [64]
            const int* __restrict__ flag_is64,
            float* __restrict__ out, int N) {
    const int tid = blockIdx.x * blockDim.x + threadIdx.x;
    const int ls  = threadIdx.x & 7;            // lane-in-group
    const int gstride = (gridDim.x * blockDim.x) >> 3;
    const int is64 = *flag_is64;                // uniform

    // channels for this lane: x0 -> 4*ls+j ; x1 -> 32+4*ls+j
    const float4 wA0 = Wpc4[4 * ls + 0];
    const float4 wA1 = Wpc4[4 * ls + 1];
    const float4 wA2 = Wpc4[4 * ls + 2];
    const float4 wA3 = Wpc4[4 * ls + 3];
    const float4 wB0 = Wpc4[32 + 4 * ls + 0];
    const float4 wB1 = Wpc4[32 + 4 * ls + 1];
    const float4 wB2 = Wpc4[32 + 4 * ls + 2];
    const float4 wB3 = Wpc4[32 + 4 * ls + 3];

#pragma unroll 2
    for (int p = tid >> 3; p < N; p += gstride) {
        // ---- leader: idx + gather first (latency hidden by FMA block) ----
        float gzx = 0.f, gzy = 0.f, gzz = 0.f;
        if (ls == 0) {
            int idx;
            if (is64) idx = (int)__builtin_nontemporal_load((const long long*)idx_raw + p);
            else      idx = __builtin_nontemporal_load((const int*)idx_raw + p);
            float4 gz = GZ4[idx];          // cached load: L2-resident table
            gzx = gz.x; gzy = gz.y; gzz = gz.z;
        }

        // ---- streaming pc reads ----
        const float* prow = pc + (size_t)p * CPC;
        f32x4 x0 = nt_load4(prow + 4 * ls);
        f32x4 x1 = nt_load4(prow + 32 + 4 * ls);

        float a0, a1, a2;
        a0 = wA0.x * x0.x;            a1 = wA0.y * x0.x;            a2 = wA0.z * x0.x;
        a0 = fmaf(wA1.x, x0.y, a0);   a1 = fmaf(wA1.y, x0.y, a1);   a2 = fmaf(wA1.z, x0.y, a2);
        a0 = fmaf(wA2.x, x0.z, a0);   a1 = fmaf(wA2.y, x0.z, a1);   a2 = fmaf(wA2.z, x0.z, a2);
        a0 = fmaf(wA3.x, x0.w, a0);   a1 = fmaf(wA3.y, x0.w, a1);   a2 = fmaf(wA3.z, x0.w, a2);
        a0 = fmaf(wB0.x, x1.x, a0);   a1 = fmaf(wB0.y, x1.x, a1);   a2 = fmaf(wB0.z, x1.x, a2);
        a0 = fmaf(wB1.x, x1.y, a0);   a1 = fmaf(wB1.y, x1.y, a1);   a2 = fmaf(wB1.z, x1.y, a2);
        a0 = fmaf(wB2.x, x1.z, a0);   a1 = fmaf(wB2.y, x1.z, a1);   a2 = fmaf(wB2.z, x1.z, a2);
        a0 = fmaf(wB3.x, x1.w, a0);   a1 = fmaf(wB3.y, x1.w, a1);   a2 = fmaf(wB3.z, x1.w, a2);

#pragma unroll
        for (int m = 1; m < 8; m <<= 1) {
            a0 += __shfl_xor(a0, m, 8);
            a1 += __shfl_xor(a1, m, 8);
            a2 += __shfl_xor(a2, m, 8);
        }

        if (ls == 0) {
            float* o = out + (size_t)p * COUT;
            __builtin_nontemporal_store(a0 + gzx, o + 0);
            __builtin_nontemporal_store(a1 + gzy, o + 1);
            __builtin_nontemporal_store(a2 + gzz, o + 2);
        }
    }
}

// ---------------------------------------------------------------------------
// Fallback if workspace is too small (need ~4.1 MB). Direct strided gather.
// ---------------------------------------------------------------------------
__global__ void __launch_bounds__(256)
direct_kernel(const float* __restrict__ grid,
              const float* __restrict__ pc,
              const void* __restrict__ idx_raw,
              const float* __restrict__ Yw, const float* __restrict__ Yb,
              const float* __restrict__ Zw, const float* __restrict__ Zb,
              float* __restrict__ out, int N) {
    int i = blockIdx.x * blockDim.x + threadIdx.x;
    if (i >= N) return;
    int idx = (int)(((const long long*)idx_raw)[i]);   // reference spec: int64

    float h[CH];
#pragma unroll
    for (int j = 0; j < CH; ++j) h[j] = Yb[j];
    for (int c = 0; c < CG; ++c) {
        float g = grid[(size_t)c * NCELLS + idx];
#pragma unroll
        for (int j = 0; j < CH; ++j) h[j] = fmaf(Yw[j * CIN + c], g, h[j]);
    }
    const float4* pcp = (const float4*)(pc + (size_t)i * CPC);
#pragma unroll 2
    for (int c4 = 0; c4 < CPC / 4; ++c4) {
        float4 x = pcp[c4];
#pragma unroll
        for (int j = 0; j < CH; ++j) {
            const float* w = Yw + j * CIN + CG + c4 * 4;
            h[j] = fmaf(w[0], x.x, h[j]); h[j] = fmaf(w[1], x.y, h[j]);
            h[j] = fmaf(w[2], x.z, h[j]); h[j] = fmaf(w[3], x.w, h[j]);
        }
    }
#pragma unroll
    for (int t = 0; t < COUT; ++t) {
        float a = Zb[t];
#pragma unroll
        for (int j = 0; j < CH; ++j) a = fmaf(Zw[t * CH + j], h[j], a);
        out[(size_t)i * COUT + t] = a;
    }
}

extern "C" void kernel_launch(void* const* d_in, const int* in_sizes, int n_in,
                              void* d_out, int out_size, void* d_ws, size_t ws_size,
                              hipStream_t stream) {
    const float* grid = (const float*)d_in[0];   // (64,512,512)
    const float* pc   = (const float*)d_in[1];   // (N,64)
    const void*  idx  = d_in[2];                 // (N,) int64 (or int32, detected)
    const float* Yw   = (const float*)d_in[3];   // (32,128)
    const float* Yb   = (const float*)d_in[4];   // (32,)
    const float* Zw   = (const float*)d_in[5];   // (3,32)
    const float* Zb   = (const float*)d_in[6];   // (3,)
    float* out = (float*)d_out;
    const int N = in_sizes[2];

    const size_t GZ_bytes = (size_t)NCELLS * sizeof(float4);   // 4 MiB
    const size_t W_bytes  = 64 * sizeof(float4);               // 1 KiB each
    const size_t need = GZ_bytes + 2 * W_bytes + sizeof(float4) + sizeof(int);

    if (ws_size >= need) {
        char* w = (char*)d_ws;
        float4* GZ4   = (float4*)w;                       w += GZ_bytes;
        float4* Wemb4 = (float4*)w;                       w += W_bytes;
        float4* Wpc4  = (float4*)w;                       w += W_bytes;
        float4* beff  = (float4*)w;                       w += sizeof(float4);
        int*    flag  = (int*)w;

        prep_kernel<<<1, 128, 0, stream>>>(Yw, Yb, Zw, Zb,
                                           (const unsigned long long*)idx,
                                           Wemb4, Wpc4, beff, flag);
        gz_kernel<<<NCELLS / 256, 256, 0, stream>>>(grid, Wemb4, beff, GZ4);
        // 8 lanes/point, grid-stride; 4096 blocks
        main_kernel<<<4096, 256, 0, stream>>>(GZ4, pc, idx, Wpc4, flag, out, N);
    } else {
        const int threads = 256;
        direct_kernel<<<(N + threads - 1) / threads, threads, 0, stream>>>(
            grid, pc, idx, Yw, Yb, Zw, Zb, out, N);
    }
}